// Round 1
// baseline (1311.181 us; speedup 1.0000x reference)
//
#include <hip/hip_runtime.h>
#include <cstdint>
#include <cstddef>

typedef __bf16 bf16_t;
typedef __bf16 bf16x4 __attribute__((ext_vector_type(4)));
typedef __bf16 bf16x8 __attribute__((ext_vector_type(8)));
typedef float f32x4 __attribute__((ext_vector_type(4)));

#define B_ 4
#define T_ 2048
#define DIM_ 2048
#define H_ 16
#define KVH_ 4
#define HD_ 128
#define QKV_ 3072
#define ATT_SCALE 0.08838834764831845f

// ---------------------------------------------------------------------------
// async global->LDS, 16B per lane. LDS dest = wave-uniform base + lane*16.
// ---------------------------------------------------------------------------
__device__ __forceinline__ void gload16(const bf16_t* g, bf16_t* l) {
  __builtin_amdgcn_global_load_lds(
      (const __attribute__((address_space(1))) unsigned int*)g,
      (__attribute__((address_space(3))) unsigned int*)l, 16, 0, 0);
}

// ---------------------------------------------------------------------------
// fp32 -> bf16 convert (vectorized)
// ---------------------------------------------------------------------------
__global__ __launch_bounds__(256) void cvt_kernel(const float4* __restrict__ in,
                                                  bf16x4* __restrict__ out, int n4) {
  int i = blockIdx.x * 256 + threadIdx.x;
  if (i < n4) {
    float4 v = in[i];
    bf16x4 o = {(__bf16)v.x, (__bf16)v.y, (__bf16)v.z, (__bf16)v.w};
    out[i] = o;
  }
}

// ---------------------------------------------------------------------------
// GEMM: C(MxN) = A(MxK) @ B(NxK)^T, bf16 in, fp32 acc. m97 structure:
// 128x128 tile, BK=32, 256 thr = 4 waves (2x2 of 64x64), global_load_lds w=16.
// ---------------------------------------------------------------------------
__global__ __launch_bounds__(256) void gemm_bt(const bf16_t* __restrict__ A,
                                               const bf16_t* __restrict__ B,
                                               void* __restrict__ Cp,
                                               int M, int N, int K, int out_bf16) {
  __shared__ bf16_t As[128 * 32];
  __shared__ bf16_t Bs[128 * 32];
  const int tid = threadIdx.x;
  const int w = tid >> 6, lane = tid & 63;
  const int m_lane = lane & 15, quad = lane >> 4;
  const int wr = w >> 1, wc = w & 1;
  const int rowBase = blockIdx.y * 128, colBase = blockIdx.x * 128;

  f32x4 acc[4][4];
#pragma unroll
  for (int i = 0; i < 4; ++i)
#pragma unroll
    for (int j = 0; j < 4; ++j) acc[i][j] = (f32x4){0.f, 0.f, 0.f, 0.f};

  const int nk = K >> 5;
  for (int kk = 0; kk < nk; ++kk) {
    const int k0 = kk << 5;
#pragma unroll
    for (int i2 = 0; i2 < 2; ++i2) {
      int idx = i2 * 256 + tid;      // 512 chunks of 16B per tile
      int row = idx >> 2, kc = idx & 3;
      gload16(A + (size_t)(rowBase + row) * K + k0 + kc * 8, &As[idx * 8]);
      gload16(B + (size_t)(colBase + row) * K + k0 + kc * 8, &Bs[idx * 8]);
    }
    __syncthreads();
    bf16x8 a[4], bb[4];
#pragma unroll
    for (int i = 0; i < 4; ++i)
      a[i] = *(const bf16x8*)&As[(wr * 64 + i * 16 + m_lane) * 32 + quad * 8];
#pragma unroll
    for (int j = 0; j < 4; ++j)
      bb[j] = *(const bf16x8*)&Bs[(wc * 64 + j * 16 + m_lane) * 32 + quad * 8];
#pragma unroll
    for (int i = 0; i < 4; ++i)
#pragma unroll
      for (int j = 0; j < 4; ++j)
        acc[i][j] = __builtin_amdgcn_mfma_f32_16x16x32_bf16(a[i], bb[j], acc[i][j], 0, 0, 0);
    __syncthreads();
  }

  if (out_bf16) {
    bf16_t* C = (bf16_t*)Cp;
#pragma unroll
    for (int i = 0; i < 4; ++i)
#pragma unroll
      for (int j = 0; j < 4; ++j)
#pragma unroll
        for (int r = 0; r < 4; ++r) {
          int row = rowBase + wr * 64 + i * 16 + quad * 4 + r;
          int col = colBase + wc * 64 + j * 16 + m_lane;
          C[(size_t)row * N + col] = (bf16_t)acc[i][j][r];
        }
  } else {
    float* C = (float*)Cp;
#pragma unroll
    for (int i = 0; i < 4; ++i)
#pragma unroll
      for (int j = 0; j < 4; ++j)
#pragma unroll
        for (int r = 0; r < 4; ++r) {
          int row = rowBase + wr * 64 + i * 16 + quad * 4 + r;
          int col = colBase + wc * 64 + j * 16 + m_lane;
          C[(size_t)row * N + col] = acc[i][j][r];
        }
  }
}

// ---------------------------------------------------------------------------
// In-place RMSNorm + RoPE (+ q_gain) over q and k head-rows of the qkv buffer.
// One wave per (token, head-row); lane covers elems {lane, lane+64} of HD=128.
// ---------------------------------------------------------------------------
__global__ __launch_bounds__(256) void qknorm_kernel(bf16_t* __restrict__ qkv,
                                                     const float* __restrict__ gain) {
  const int w = threadIdx.x >> 6, lane = threadIdx.x & 63;
  const int gid = blockIdx.x * 4 + w;          // B*T*(H+KVH) rows
  const int token = gid / 20, head = gid % 20;
  const int t = token & (T_ - 1);
  const bool isq = head < H_;
  const int col = isq ? head * HD_ : DIM_ + (head - H_) * HD_;
  bf16_t* p = qkv + (size_t)token * QKV_ + col;

  float v0 = (float)p[lane];
  float v1 = (float)p[lane + 64];
  float ss = v0 * v0 + v1 * v1;
#pragma unroll
  for (int off = 32; off; off >>= 1) ss += __shfl_xor(ss, off, 64);
  float r = rsqrtf(ss * (1.f / 128.f) + 1e-6f);
  v0 *= r;
  v1 *= r;
  // RoPE on first 64 elems: pairs (d, d+32), d<32
  float partner = __shfl_xor(v0, 32, 64);
  int i = lane & 31;
  // inv_freq = 10000^(-2i/64) = 2^(-(2i/64)*log2(10000))
  float inv_freq = exp2f(-(float)(2 * i) * (1.f / 64.f) * 13.287712379549449f);
  float ang = (float)t * inv_freq;
  float cs = cosf(ang), sn = sinf(ang);
  float rot = (lane < 32) ? (v0 * cs - partner * sn) : (v0 * cs + partner * sn);
  float g = isq ? gain[head] : 1.f;
  p[lane] = (bf16_t)(rot * g);
  p[lane + 64] = (bf16_t)(v1 * g);
}

// ---------------------------------------------------------------------------
// V transpose: (B,T,KVH,HD) section of qkv -> vT (B,KVH,HD,T), bf16.
// ---------------------------------------------------------------------------
__global__ __launch_bounds__(256) void vtrans_kernel(const bf16_t* __restrict__ qkv,
                                                     bf16_t* __restrict__ vt) {
  const int bk = blockIdx.x;  // b*KVH + kvh
  const int t0 = blockIdx.y * 64;
  const int b = bk >> 2, kvh = bk & 3;
  __shared__ bf16_t tile[64][132];  // +4 pad (stride 264B, 8B-aligned)
  const bf16_t* src = qkv + (size_t)(b * T_) * QKV_ + DIM_ + KVH_ * HD_ + kvh * HD_;
  for (int c = threadIdx.x; c < 2048; c += 256) {
    int tl = c >> 5, h4 = c & 31;
    bf16x4 v = *(const bf16x4*)(src + (size_t)(t0 + tl) * QKV_ + h4 * 4);
    *(bf16x4*)&tile[tl][h4 * 4] = v;
  }
  __syncthreads();
  bf16_t* dst = vt + (size_t)bk * HD_ * T_;
  for (int c = threadIdx.x; c < 2048; c += 256) {
    int hd = c >> 4, t4 = c & 15;
    bf16x4 v = {tile[t4 * 4 + 0][hd], tile[t4 * 4 + 1][hd],
                tile[t4 * 4 + 2][hd], tile[t4 * 4 + 3][hd]};
    *(bf16x4*)(dst + (size_t)hd * T_ + t0 + t4 * 4) = v;
  }
}

// ---------------------------------------------------------------------------
// Flash attention + v-hat projection removal.
// Grid (T/64, H, B), 256 thr = 4 waves. Wave = 16 Q rows, 32 keys/iter.
// MFMA 16x16x32 bf16. C layout: col=lane&15, row=quad*4+reg (verified m89/91).
// A layout: A[m=lane&15][k=quad*8+j]; B layout: B[k=quad*8+j][n=lane&15].
// P relayout C->A via per-wave LDS round-trip (m120-verified transform).
// ---------------------------------------------------------------------------
__global__ __launch_bounds__(256) void attn_kernel(const bf16_t* __restrict__ qkv,
                                                   const bf16_t* __restrict__ vt,
                                                   bf16_t* __restrict__ y) {
  const int w = threadIdx.x >> 6, lane = threadIdx.x & 63;
  const int m_lane = lane & 15, quad = lane >> 4;
  const int h = blockIdx.y, b = blockIdx.z, kvh = h >> 2;
  const int qbase = blockIdx.x * 64 + w * 16;

  __shared__ bf16_t plds[4][16][32];  // per-wave P tile (16 q x 32 k)

  const bf16_t* qptr = qkv + (size_t)(b * T_) * QKV_ + h * HD_;
  const bf16_t* kptr = qkv + (size_t)(b * T_) * QKV_ + DIM_ + kvh * HD_;
  const bf16_t* vptr = qkv + (size_t)(b * T_) * QKV_ + DIM_ + KVH_ * HD_ + kvh * HD_;
  const bf16_t* vtptr = vt + (size_t)(b * KVH_ + kvh) * HD_ * T_;

  // Q fragments (A-operand), kept in registers for whole K loop
  bf16x8 aq[4];
#pragma unroll
  for (int c = 0; c < 4; ++c)
    aq[c] = *(const bf16x8*)(qptr + (size_t)(qbase + m_lane) * QKV_ + c * 32 + quad * 8);

  f32x4 o[8];
#pragma unroll
  for (int f = 0; f < 8; ++f) o[f] = (f32x4){0.f, 0.f, 0.f, 0.f};
  float m_r[4] = {-1e30f, -1e30f, -1e30f, -1e30f};
  float l_r[4] = {0.f, 0.f, 0.f, 0.f};

  const int iters = (qbase + 47) >> 5;  // ceil((qbase+16)/32)
  for (int it = 0; it < iters; ++it) {
    const int kb = it << 5;
    f32x4 S0 = (f32x4){0.f, 0.f, 0.f, 0.f};
    f32x4 S1 = (f32x4){0.f, 0.f, 0.f, 0.f};
#pragma unroll
    for (int c = 0; c < 4; ++c) {
      bf16x8 b0 = *(const bf16x8*)(kptr + (size_t)(kb + m_lane) * QKV_ + c * 32 + quad * 8);
      bf16x8 b1 = *(const bf16x8*)(kptr + (size_t)(kb + 16 + m_lane) * QKV_ + c * 32 + quad * 8);
      S0 = __builtin_amdgcn_mfma_f32_16x16x32_bf16(aq[c], b0, S0, 0, 0, 0);
      S1 = __builtin_amdgcn_mfma_f32_16x16x32_bf16(aq[c], b1, S1, 0, 0, 0);
    }
    // scale + causal mask
    float s0v[4], s1v[4];
#pragma unroll
    for (int r = 0; r < 4; ++r) {
      int row = qbase + quad * 4 + r;
      s0v[r] = (kb + m_lane <= row) ? S0[r] * ATT_SCALE : -1e30f;
      s1v[r] = (kb + 16 + m_lane <= row) ? S1[r] * ATT_SCALE : -1e30f;
    }
    // rowwise max over 32 cols (16-lane butterfly)
    float mx[4];
#pragma unroll
    for (int r = 0; r < 4; ++r) mx[r] = fmaxf(s0v[r], s1v[r]);
#pragma unroll
    for (int off = 8; off; off >>= 1)
#pragma unroll
      for (int r = 0; r < 4; ++r) mx[r] = fmaxf(mx[r], __shfl_xor(mx[r], off, 16));
    // online softmax update
    float p0[4], p1[4], rs[4];
#pragma unroll
    for (int r = 0; r < 4; ++r) {
      float mn = fmaxf(m_r[r], mx[r]);
      float al = __expf(m_r[r] - mn);
      m_r[r] = mn;
      p0[r] = __expf(s0v[r] - mn);
      p1[r] = __expf(s1v[r] - mn);
      rs[r] = p0[r] + p1[r];
      l_r[r] *= al;
#pragma unroll
      for (int f = 0; f < 8; ++f) o[f][r] *= al;
    }
#pragma unroll
    for (int off = 8; off; off >>= 1)
#pragma unroll
      for (int r = 0; r < 4; ++r) rs[r] += __shfl_xor(rs[r], off, 16);
#pragma unroll
    for (int r = 0; r < 4; ++r) l_r[r] += rs[r];

    // P: C-layout -> LDS -> A-layout
#pragma unroll
    for (int r = 0; r < 4; ++r) {
      plds[w][quad * 4 + r][m_lane] = (bf16_t)p0[r];
      plds[w][quad * 4 + r][16 + m_lane] = (bf16_t)p1[r];
    }
    asm volatile("s_waitcnt lgkmcnt(0)" ::: "memory");
    bf16x8 pa = *(const bf16x8*)&plds[w][m_lane][quad * 8];
    // PV
#pragma unroll
    for (int f = 0; f < 8; ++f) {
      bf16x8 vb = *(const bf16x8*)(vtptr + (size_t)(f * 16 + m_lane) * T_ + kb + quad * 8);
      o[f] = __builtin_amdgcn_mfma_f32_16x16x32_bf16(pa, vb, o[f], 0, 0, 0);
    }
  }

  // epilogue: normalize by l, remove projection onto vn, store bf16 y (B,T,H*HD)
#pragma unroll
  for (int r = 0; r < 4; ++r) {
    const int trow = qbase + quad * 4 + r;
    const float linv = 1.f / l_r[r];
    float yv[8], vv[8];
#pragma unroll
    for (int f = 0; f < 8; ++f) {
      vv[f] = (float)vptr[(size_t)trow * QKV_ + f * 16 + m_lane];
      yv[f] = o[f][r] * linv;
    }
    float n2 = 0.f, dp = 0.f;
#pragma unroll
    for (int f = 0; f < 8; ++f) {
      n2 += vv[f] * vv[f];
      dp += yv[f] * vv[f];
    }
#pragma unroll
    for (int off = 8; off; off >>= 1) {
      n2 += __shfl_xor(n2, off, 16);
      dp += __shfl_xor(dp, off, 16);
    }
    float d = fmaxf(sqrtf(n2), 1e-12f);
    float coef = dp / (d * d);
#pragma unroll
    for (int f = 0; f < 8; ++f)
      y[(size_t)(b * T_ + trow) * DIM_ + h * HD_ + f * 16 + m_lane] =
          (bf16_t)(yv[f] - coef * vv[f]);
  }
}

// ---------------------------------------------------------------------------
extern "C" void kernel_launch(void* const* d_in, const int* in_sizes, int n_in,
                              void* d_out, int out_size, void* d_ws, size_t ws_size,
                              hipStream_t stream) {
  const float* x = (const float*)d_in[0];
  const float* Wq = (const float*)d_in[1];
  const float* Wk = (const float*)d_in[2];
  const float* Wv = (const float*)d_in[3];
  const float* Wp = (const float*)d_in[4];
  const float* qg = (const float*)d_in[5];

  // workspace layout (bf16 elems). xbf reused as y after gemm1 consumes it.
  bf16_t* xbf = (bf16_t*)d_ws;                        // 8192*2048
  bf16_t* wqkv = xbf + (size_t)8192 * 2048;           // 3072*2048
  bf16_t* wproj = wqkv + (size_t)3072 * 2048;         // 2048*2048
  bf16_t* qkv = wproj + (size_t)2048 * 2048;          // 8192*3072
  bf16_t* vt = qkv + (size_t)8192 * 3072;             // 16*128*2048
  bf16_t* ybf = xbf;

  cvt_kernel<<<16384, 256, 0, stream>>>((const float4*)x, (bf16x4*)xbf, 4194304);
  cvt_kernel<<<4096, 256, 0, stream>>>((const float4*)Wq, (bf16x4*)wqkv, 1048576);
  cvt_kernel<<<1024, 256, 0, stream>>>((const float4*)Wk, (bf16x4*)(wqkv + (size_t)2048 * 2048), 262144);
  cvt_kernel<<<1024, 256, 0, stream>>>((const float4*)Wv, (bf16x4*)(wqkv + (size_t)2560 * 2048), 262144);
  cvt_kernel<<<4096, 256, 0, stream>>>((const float4*)Wp, (bf16x4*)wproj, 1048576);

  gemm_bt<<<dim3(24, 64), 256, 0, stream>>>(xbf, wqkv, qkv, 8192, 3072, 2048, 1);
  qknorm_kernel<<<40960, 256, 0, stream>>>(qkv, qg);
  vtrans_kernel<<<dim3(16, 32), 256, 0, stream>>>(qkv, vt);
  attn_kernel<<<dim3(32, 16, 4), 256, 0, stream>>>(qkv, vt, ybf);
  gemm_bt<<<dim3(16, 64), 256, 0, stream>>>(ybf, wproj, d_out, 8192, 2048, 2048, 0);
}

// Round 2
// 777.711 us; speedup vs baseline: 1.6859x; 1.6859x over previous
//
#include <hip/hip_runtime.h>
#include <cstdint>
#include <cstddef>

typedef __bf16 bf16_t;
typedef __bf16 bf16x4 __attribute__((ext_vector_type(4)));
typedef __bf16 bf16x8 __attribute__((ext_vector_type(8)));
typedef float f32x4 __attribute__((ext_vector_type(4)));

#define B_ 4
#define T_ 2048
#define DIM_ 2048
#define H_ 16
#define KVH_ 4
#define HD_ 128
#define QKV_ 3072
// SCALE * log2(e): folded into q rows at qknorm time; attn uses exp2.
#define QSCALE (0.08838834764831845f * 1.4426950408889634f)

// ---------------------------------------------------------------------------
// async global->LDS, 16B per lane. LDS dest = wave-uniform base + lane*16.
// ---------------------------------------------------------------------------
__device__ __forceinline__ void gload16(const bf16_t* g, bf16_t* l) {
  __builtin_amdgcn_global_load_lds(
      (const __attribute__((address_space(1))) unsigned int*)g,
      (__attribute__((address_space(3))) unsigned int*)l, 16, 0, 0);
}

// ---------------------------------------------------------------------------
// fp32 -> bf16 convert (vectorized)
// ---------------------------------------------------------------------------
__global__ __launch_bounds__(256) void cvt_kernel(const float4* __restrict__ in,
                                                  bf16x4* __restrict__ out, int n4) {
  int i = blockIdx.x * 256 + threadIdx.x;
  if (i < n4) {
    float4 v = in[i];
    bf16x4 o = {(__bf16)v.x, (__bf16)v.y, (__bf16)v.z, (__bf16)v.w};
    out[i] = o;
  }
}

// ---------------------------------------------------------------------------
// GEMM: C(MxN) = A(MxK) @ B(NxK)^T, bf16 in, fp32 acc. m97 structure.
// ---------------------------------------------------------------------------
__global__ __launch_bounds__(256) void gemm_bt(const bf16_t* __restrict__ A,
                                               const bf16_t* __restrict__ B,
                                               void* __restrict__ Cp,
                                               int M, int N, int K, int out_bf16) {
  __shared__ bf16_t As[128 * 32];
  __shared__ bf16_t Bs[128 * 32];
  const int tid = threadIdx.x;
  const int w = tid >> 6, lane = tid & 63;
  const int m_lane = lane & 15, quad = lane >> 4;
  const int wr = w >> 1, wc = w & 1;
  const int rowBase = blockIdx.y * 128, colBase = blockIdx.x * 128;

  f32x4 acc[4][4];
#pragma unroll
  for (int i = 0; i < 4; ++i)
#pragma unroll
    for (int j = 0; j < 4; ++j) acc[i][j] = (f32x4){0.f, 0.f, 0.f, 0.f};

  const int nk = K >> 5;
  for (int kk = 0; kk < nk; ++kk) {
    const int k0 = kk << 5;
#pragma unroll
    for (int i2 = 0; i2 < 2; ++i2) {
      int idx = i2 * 256 + tid;
      int row = idx >> 2, kc = idx & 3;
      gload16(A + (size_t)(rowBase + row) * K + k0 + kc * 8, &As[idx * 8]);
      gload16(B + (size_t)(colBase + row) * K + k0 + kc * 8, &Bs[idx * 8]);
    }
    __syncthreads();
    bf16x8 a[4], bb[4];
#pragma unroll
    for (int i = 0; i < 4; ++i)
      a[i] = *(const bf16x8*)&As[(wr * 64 + i * 16 + m_lane) * 32 + quad * 8];
#pragma unroll
    for (int j = 0; j < 4; ++j)
      bb[j] = *(const bf16x8*)&Bs[(wc * 64 + j * 16 + m_lane) * 32 + quad * 8];
#pragma unroll
    for (int i = 0; i < 4; ++i)
#pragma unroll
      for (int j = 0; j < 4; ++j)
        acc[i][j] = __builtin_amdgcn_mfma_f32_16x16x32_bf16(a[i], bb[j], acc[i][j], 0, 0, 0);
    __syncthreads();
  }

  if (out_bf16) {
    bf16_t* C = (bf16_t*)Cp;
#pragma unroll
    for (int i = 0; i < 4; ++i)
#pragma unroll
      for (int j = 0; j < 4; ++j)
#pragma unroll
        for (int r = 0; r < 4; ++r) {
          int row = rowBase + wr * 64 + i * 16 + quad * 4 + r;
          int col = colBase + wc * 64 + j * 16 + m_lane;
          C[(size_t)row * N + col] = (bf16_t)acc[i][j][r];
        }
  } else {
    float* C = (float*)Cp;
#pragma unroll
    for (int i = 0; i < 4; ++i)
#pragma unroll
      for (int j = 0; j < 4; ++j)
#pragma unroll
        for (int r = 0; r < 4; ++r) {
          int row = rowBase + wr * 64 + i * 16 + quad * 4 + r;
          int col = colBase + wc * 64 + j * 16 + m_lane;
          C[(size_t)row * N + col] = acc[i][j][r];
        }
  }
}

// ---------------------------------------------------------------------------
// In-place RMSNorm + RoPE over q and k head-rows. q rows additionally get
// gain * SCALE * log2(e) so attn can use exp2 with no per-score multiply.
// ---------------------------------------------------------------------------
__global__ __launch_bounds__(256) void qknorm_kernel(bf16_t* __restrict__ qkv,
                                                     const float* __restrict__ gain) {
  const int w = threadIdx.x >> 6, lane = threadIdx.x & 63;
  const int gid = blockIdx.x * 4 + w;
  const int token = gid / 20, head = gid % 20;
  const int t = token & (T_ - 1);
  const bool isq = head < H_;
  const int col = isq ? head * HD_ : DIM_ + (head - H_) * HD_;
  bf16_t* p = qkv + (size_t)token * QKV_ + col;

  float v0 = (float)p[lane];
  float v1 = (float)p[lane + 64];
  float ss = v0 * v0 + v1 * v1;
#pragma unroll
  for (int off = 32; off; off >>= 1) ss += __shfl_xor(ss, off, 64);
  float r = rsqrtf(ss * (1.f / 128.f) + 1e-6f);
  v0 *= r;
  v1 *= r;
  float partner = __shfl_xor(v0, 32, 64);
  int i = lane & 31;
  float inv_freq = exp2f(-(float)(2 * i) * (1.f / 64.f) * 13.287712379549449f);
  float ang = (float)t * inv_freq;
  float cs = cosf(ang), sn = sinf(ang);
  float rot = (lane < 32) ? (v0 * cs - partner * sn) : (v0 * cs + partner * sn);
  float g = isq ? gain[head] * QSCALE : 1.f;
  p[lane] = (bf16_t)(rot * g);
  p[lane + 64] = (bf16_t)(v1 * g);
}

// ---------------------------------------------------------------------------
// V transpose: (B,T,KVH,HD) section of qkv -> vT (B,KVH,HD,T), bf16.
// ---------------------------------------------------------------------------
__global__ __launch_bounds__(256) void vtrans_kernel(const bf16_t* __restrict__ qkv,
                                                     bf16_t* __restrict__ vt) {
  const int bk = blockIdx.x;
  const int t0 = blockIdx.y * 64;
  const int b = bk >> 2, kvh = bk & 3;
  __shared__ bf16_t tile[64][132];
  const bf16_t* src = qkv + (size_t)(b * T_) * QKV_ + DIM_ + KVH_ * HD_ + kvh * HD_;
  for (int c = threadIdx.x; c < 2048; c += 256) {
    int tl = c >> 5, h4 = c & 31;
    bf16x4 v = *(const bf16x4*)(src + (size_t)(t0 + tl) * QKV_ + h4 * 4);
    *(bf16x4*)&tile[tl][h4 * 4] = v;
  }
  __syncthreads();
  bf16_t* dst = vt + (size_t)bk * HD_ * T_;
  for (int c = threadIdx.x; c < 2048; c += 256) {
    int hd = c >> 4, t4 = c & 15;
    bf16x4 v = {tile[t4 * 4 + 0][hd], tile[t4 * 4 + 1][hd],
                tile[t4 * 4 + 2][hd], tile[t4 * 4 + 3][hd]};
    *(bf16x4*)(dst + (size_t)hd * T_ + t0 + t4 * 4) = v;
  }
}

// ---------------------------------------------------------------------------
// Flash attention, S^T formulation. Block = 128 Q rows, 4 waves x 32 rows.
// K-step = 64 keys, K & V^T staged in LDS (XOR-swizzled, async).
// S^T = K.Q^T  (A=K[m=key][k=hd], B=Q^T[k=hd][n=qrow])
//  -> C-frag: lane(q,m) reg r = S^T[key=kf*16+q*4+r][qrow=qf*16+m]
//     (4 consecutive KEYS per reg quad -> packed b64 P writes)
// P stored row-major [qrow][key] (stride 72) -> ds_read_b128 B-frags for PV.
// O^T = V^T.P^T -> lane(q,m) reg r = O^T[d=f*16+q*4+r][qrow=qf*16+m]
//  -> packed 8B y stores.
// ---------------------------------------------------------------------------
__global__ __launch_bounds__(256) void attn_kernel(const bf16_t* __restrict__ qkv,
                                                   const bf16_t* __restrict__ vt,
                                                   bf16_t* __restrict__ y) {
  __shared__ __align__(16) bf16_t Ks[64 * 128];   // [key][hd], hd-chunks XOR key&15
  __shared__ __align__(16) bf16_t Vs[128 * 64];   // [d][key], key-chunks XOR d&7
  __shared__ __align__(16) bf16_t Ps[4][32 * 72]; // per-wave P [qrow][key], pad 72

  const int tid = threadIdx.x;
  const int w = tid >> 6, lane = tid & 63;
  const int m = lane & 15, q = lane >> 4;
  const int h = blockIdx.y, b = blockIdx.z, kvh = h >> 2;
  const int qb = blockIdx.x * 128;
  const int qbw = qb + w * 32;

  const bf16_t* qptr = qkv + (size_t)(b * T_) * QKV_ + h * HD_;
  const bf16_t* kptr = qkv + (size_t)(b * T_) * QKV_ + DIM_ + kvh * HD_;
  const bf16_t* vptr = qkv + (size_t)(b * T_) * QKV_ + DIM_ + KVH_ * HD_ + kvh * HD_;
  const bf16_t* vtptr = vt + (size_t)(b * KVH_ + kvh) * HD_ * T_;

  // Q fragments: B-operand for S^T. aq[qf][c] = Q[qbw+qf*16+m][c*32+q*8 ..+8]
  bf16x8 aq[2][4];
#pragma unroll
  for (int qf = 0; qf < 2; ++qf)
#pragma unroll
    for (int c = 0; c < 4; ++c)
      aq[qf][c] = *(const bf16x8*)(qptr + (size_t)(qbw + qf * 16 + m) * QKV_ + c * 32 + q * 8);

  f32x4 o[2][8];
#pragma unroll
  for (int qf = 0; qf < 2; ++qf)
#pragma unroll
    for (int f = 0; f < 8; ++f) o[qf][f] = (f32x4){0.f, 0.f, 0.f, 0.f};
  float m_r[2] = {-1e30f, -1e30f};
  float l_r[2] = {0.f, 0.f};

  // staging source indices (fixed per thread across iters)
  // K: 1024 chunks: L = i*256+tid (i=0..3): key=L>>4, s=L&15, src hd-chunk s^(key&15)
  // V: 1024 chunks: idx = i*256+tid-1024 (i=4..7): d=idx>>3, s=idx&7, chunk s^(d&7)
  const int kend = qb + 128;
  for (int kb = 0; kb < kend; kb += 64) {
#pragma unroll
    for (int i = 0; i < 4; ++i) {
      int L = i * 256 + tid;
      int key = L >> 4, s = L & 15;
      gload16(kptr + (size_t)(kb + key) * QKV_ + ((s ^ key) & 15) * 8, &Ks[L * 8]);
    }
#pragma unroll
    for (int i = 0; i < 4; ++i) {
      int idx = i * 256 + tid;
      int d = idx >> 3, s = idx & 7;
      gload16(vtptr + (size_t)d * T_ + kb + ((s ^ d) & 7) * 8, &Vs[idx * 8]);
    }
    __syncthreads();

    // ---- S^T = K . Q^T
    f32x4 S[2][4];
#pragma unroll
    for (int qf = 0; qf < 2; ++qf)
#pragma unroll
      for (int kf = 0; kf < 4; ++kf) S[qf][kf] = (f32x4){0.f, 0.f, 0.f, 0.f};
#pragma unroll
    for (int kf = 0; kf < 4; ++kf)
#pragma unroll
      for (int c = 0; c < 4; ++c) {
        bf16x8 ak = *(const bf16x8*)&Ks[(kf * 16 + m) * 128 + ((c * 4 + q) ^ m) * 8];
        S[0][kf] = __builtin_amdgcn_mfma_f32_16x16x32_bf16(ak, aq[0][c], S[0][kf], 0, 0, 0);
        S[1][kf] = __builtin_amdgcn_mfma_f32_16x16x32_bf16(ak, aq[1][c], S[1][kf], 0, 0, 0);
      }

    const bool needmask = (kb + 63) > qbw;
    // ---- online softmax per qf (rows = qrow = m; keys spread over kf, q, r)
#pragma unroll
    for (int qf = 0; qf < 2; ++qf) {
      const int qrow = qbw + qf * 16 + m;
      if (needmask) {
#pragma unroll
        for (int kf = 0; kf < 4; ++kf)
#pragma unroll
          for (int r = 0; r < 4; ++r) {
            int key = kb + kf * 16 + q * 4 + r;
            if (key > qrow) S[qf][kf][r] = -1e30f;
          }
      }
      float t = -1e30f;
#pragma unroll
      for (int kf = 0; kf < 4; ++kf) {
        t = fmaxf(t, fmaxf(fmaxf(S[qf][kf][0], S[qf][kf][1]),
                           fmaxf(S[qf][kf][2], S[qf][kf][3])));
      }
      t = fmaxf(t, __shfl_xor(t, 16));
      t = fmaxf(t, __shfl_xor(t, 32));
      float mn = fmaxf(m_r[qf], t);
      float al = exp2f(m_r[qf] - mn);
      m_r[qf] = mn;
      float rs = 0.f;
#pragma unroll
      for (int kf = 0; kf < 4; ++kf)
#pragma unroll
        for (int r = 0; r < 4; ++r) {
          float p = exp2f(S[qf][kf][r] - mn);
          S[qf][kf][r] = p;
          rs += p;
        }
      rs += __shfl_xor(rs, 16);
      rs += __shfl_xor(rs, 32);
      l_r[qf] = l_r[qf] * al + rs;
#pragma unroll
      for (int f = 0; f < 8; ++f) {
        o[qf][f][0] *= al; o[qf][f][1] *= al; o[qf][f][2] *= al; o[qf][f][3] *= al;
      }
      // P write: packed 4 consecutive keys
#pragma unroll
      for (int kf = 0; kf < 4; ++kf) {
        bf16x4 pk = {(__bf16)S[qf][kf][0], (__bf16)S[qf][kf][1],
                     (__bf16)S[qf][kf][2], (__bf16)S[qf][kf][3]};
        *(bf16x4*)&Ps[w][(qf * 16 + m) * 72 + kf * 16 + q * 4] = pk;
      }
    }
    asm volatile("s_waitcnt lgkmcnt(0)" ::: "memory");

    // ---- PV: O^T += V^T . P^T
    bf16x8 Pb[2][2];
#pragma unroll
    for (int qf = 0; qf < 2; ++qf)
#pragma unroll
      for (int kc = 0; kc < 2; ++kc)
        Pb[qf][kc] = *(const bf16x8*)&Ps[w][(qf * 16 + m) * 72 + kc * 32 + q * 8];
#pragma unroll
    for (int f = 0; f < 8; ++f)
#pragma unroll
      for (int kc = 0; kc < 2; ++kc) {
        bf16x8 av = *(const bf16x8*)&Vs[(f * 16 + m) * 64 + (((kc * 4 + q) ^ m) & 7) * 8];
        o[0][f] = __builtin_amdgcn_mfma_f32_16x16x32_bf16(av, Pb[0][kc], o[0][f], 0, 0, 0);
        o[1][f] = __builtin_amdgcn_mfma_f32_16x16x32_bf16(av, Pb[1][kc], o[1][f], 0, 0, 0);
      }
    __syncthreads();
  }

  // ---- epilogue: y = o/l minus projection onto normalized v row
#pragma unroll
  for (int qf = 0; qf < 2; ++qf) {
    const int trow = qbw + qf * 16 + m;
    const float linv = 1.f / l_r[qf];
    bf16x4 vv[8];
    float n2 = 0.f, dp = 0.f;
#pragma unroll
    for (int f = 0; f < 8; ++f) {
      vv[f] = *(const bf16x4*)(vptr + (size_t)trow * QKV_ + f * 16 + q * 4);
#pragma unroll
      for (int r = 0; r < 4; ++r) {
        float v = (float)vv[f][r];
        n2 += v * v;
        dp += o[qf][f][r] * linv * v;
      }
    }
    n2 += __shfl_xor(n2, 16); n2 += __shfl_xor(n2, 32);
    dp += __shfl_xor(dp, 16); dp += __shfl_xor(dp, 32);
    float d = fmaxf(sqrtf(n2), 1e-12f);
    float coef = dp / (d * d);
#pragma unroll
    for (int f = 0; f < 8; ++f) {
      bf16x4 yo;
#pragma unroll
      for (int r = 0; r < 4; ++r)
        yo[r] = (bf16_t)(o[qf][f][r] * linv - coef * (float)vv[f][r]);
      *(bf16x4*)(y + (size_t)(b * T_ + trow) * DIM_ + h * HD_ + f * 16 + q * 4) = yo;
    }
  }
}

// ---------------------------------------------------------------------------
extern "C" void kernel_launch(void* const* d_in, const int* in_sizes, int n_in,
                              void* d_out, int out_size, void* d_ws, size_t ws_size,
                              hipStream_t stream) {
  const float* x = (const float*)d_in[0];
  const float* Wq = (const float*)d_in[1];
  const float* Wk = (const float*)d_in[2];
  const float* Wv = (const float*)d_in[3];
  const float* Wp = (const float*)d_in[4];
  const float* qg = (const float*)d_in[5];

  bf16_t* xbf = (bf16_t*)d_ws;                        // 8192*2048
  bf16_t* wqkv = xbf + (size_t)8192 * 2048;           // 3072*2048
  bf16_t* wproj = wqkv + (size_t)3072 * 2048;         // 2048*2048
  bf16_t* qkv = wproj + (size_t)2048 * 2048;          // 8192*3072
  bf16_t* vt = qkv + (size_t)8192 * 3072;             // 16*128*2048
  bf16_t* ybf = xbf;

  cvt_kernel<<<16384, 256, 0, stream>>>((const float4*)x, (bf16x4*)xbf, 4194304);
  cvt_kernel<<<4096, 256, 0, stream>>>((const float4*)Wq, (bf16x4*)wqkv, 1048576);
  cvt_kernel<<<1024, 256, 0, stream>>>((const float4*)Wk, (bf16x4*)(wqkv + (size_t)2048 * 2048), 262144);
  cvt_kernel<<<1024, 256, 0, stream>>>((const float4*)Wv, (bf16x4*)(wqkv + (size_t)2560 * 2048), 262144);
  cvt_kernel<<<4096, 256, 0, stream>>>((const float4*)Wp, (bf16x4*)wproj, 1048576);

  gemm_bt<<<dim3(24, 64), 256, 0, stream>>>(xbf, wqkv, qkv, 8192, 3072, 2048, 1);
  qknorm_kernel<<<40960, 256, 0, stream>>>(qkv, qg);
  vtrans_kernel<<<dim3(16, 32), 256, 0, stream>>>(qkv, vt);
  attn_kernel<<<dim3(16, 16, 4), 256, 0, stream>>>(qkv, vt, ybf);
  gemm_bt<<<dim3(16, 64), 256, 0, stream>>>(ybf, wproj, d_out, 8192, 2048, 2048, 0);
}

// Round 4
// 606.149 us; speedup vs baseline: 2.1631x; 1.2830x over previous
//
#include <hip/hip_runtime.h>
#include <cstdint>
#include <cstddef>

typedef __bf16 bf16_t;
typedef __bf16 bf16x4 __attribute__((ext_vector_type(4)));
typedef __bf16 bf16x8 __attribute__((ext_vector_type(8)));
typedef float f32x4 __attribute__((ext_vector_type(4)));

#define B_ 4
#define T_ 2048
#define DIM_ 2048
#define H_ 16
#define KVH_ 4
#define HD_ 128
#define QKV_ 3072
// SCALE * log2(e): folded into q rows at qknorm time; attn uses exp2.
#define QSCALE (0.08838834764831845f * 1.4426950408889634f)

// ---------------------------------------------------------------------------
// async global->LDS, 16B per lane. LDS dest = wave-uniform base + lane*16B.
// NOTE: dest pointer arithmetic is in ELEMENTS: 8 bf16 = 16B per lane.
// ---------------------------------------------------------------------------
__device__ __forceinline__ void gload16(const bf16_t* g, bf16_t* l) {
  __builtin_amdgcn_global_load_lds(
      (const __attribute__((address_space(1))) unsigned int*)g,
      (__attribute__((address_space(3))) unsigned int*)l, 16, 0, 0);
}

// ---------------------------------------------------------------------------
// fp32 -> bf16 convert (vectorized)
// ---------------------------------------------------------------------------
__global__ __launch_bounds__(256) void cvt_kernel(const float4* __restrict__ in,
                                                  bf16x4* __restrict__ out, int n4) {
  int i = blockIdx.x * 256 + threadIdx.x;
  if (i < n4) {
    float4 v = in[i];
    bf16x4 o = {(__bf16)v.x, (__bf16)v.y, (__bf16)v.z, (__bf16)v.w};
    out[i] = o;
  }
}

// ---------------------------------------------------------------------------
// GEMM: C(MxN) = A(MxK) @ B(NxK)^T, bf16 in, fp32 acc. m97 structure.
// ---------------------------------------------------------------------------
__global__ __launch_bounds__(256) void gemm_bt(const bf16_t* __restrict__ A,
                                               const bf16_t* __restrict__ B,
                                               void* __restrict__ Cp,
                                               int M, int N, int K, int out_bf16) {
  __shared__ bf16_t As[128 * 32];
  __shared__ bf16_t Bs[128 * 32];
  const int tid = threadIdx.x;
  const int w = tid >> 6, lane = tid & 63;
  const int m_lane = lane & 15, quad = lane >> 4;
  const int wr = w >> 1, wc = w & 1;
  const int rowBase = blockIdx.y * 128, colBase = blockIdx.x * 128;

  f32x4 acc[4][4];
#pragma unroll
  for (int i = 0; i < 4; ++i)
#pragma unroll
    for (int j = 0; j < 4; ++j) acc[i][j] = (f32x4){0.f, 0.f, 0.f, 0.f};

  const int nk = K >> 5;
  for (int kk = 0; kk < nk; ++kk) {
    const int k0 = kk << 5;
#pragma unroll
    for (int i2 = 0; i2 < 2; ++i2) {
      int idx = i2 * 256 + tid;
      int row = idx >> 2, kc = idx & 3;
      gload16(A + (size_t)(rowBase + row) * K + k0 + kc * 8, &As[idx * 8]);
      gload16(B + (size_t)(colBase + row) * K + k0 + kc * 8, &Bs[idx * 8]);
    }
    __syncthreads();
    bf16x8 a[4], bb[4];
#pragma unroll
    for (int i = 0; i < 4; ++i)
      a[i] = *(const bf16x8*)&As[(wr * 64 + i * 16 + m_lane) * 32 + quad * 8];
#pragma unroll
    for (int j = 0; j < 4; ++j)
      bb[j] = *(const bf16x8*)&Bs[(wc * 64 + j * 16 + m_lane) * 32 + quad * 8];
#pragma unroll
    for (int i = 0; i < 4; ++i)
#pragma unroll
      for (int j = 0; j < 4; ++j)
        acc[i][j] = __builtin_amdgcn_mfma_f32_16x16x32_bf16(a[i], bb[j], acc[i][j], 0, 0, 0);
    __syncthreads();
  }

  if (out_bf16) {
    bf16_t* C = (bf16_t*)Cp;
#pragma unroll
    for (int i = 0; i < 4; ++i)
#pragma unroll
      for (int j = 0; j < 4; ++j)
#pragma unroll
        for (int r = 0; r < 4; ++r) {
          int row = rowBase + wr * 64 + i * 16 + quad * 4 + r;
          int col = colBase + wc * 64 + j * 16 + m_lane;
          C[(size_t)row * N + col] = (bf16_t)acc[i][j][r];
        }
  } else {
    float* C = (float*)Cp;
#pragma unroll
    for (int i = 0; i < 4; ++i)
#pragma unroll
      for (int j = 0; j < 4; ++j)
#pragma unroll
        for (int r = 0; r < 4; ++r) {
          int row = rowBase + wr * 64 + i * 16 + quad * 4 + r;
          int col = colBase + wc * 64 + j * 16 + m_lane;
          C[(size_t)row * N + col] = acc[i][j][r];
        }
  }
}

// ---------------------------------------------------------------------------
// In-place RMSNorm + RoPE over q and k head-rows. q rows additionally get
// gain * SCALE * log2(e) so attn can use exp2 with no per-score multiply.
// ---------------------------------------------------------------------------
__global__ __launch_bounds__(256) void qknorm_kernel(bf16_t* __restrict__ qkv,
                                                     const float* __restrict__ gain) {
  const int w = threadIdx.x >> 6, lane = threadIdx.x & 63;
  const int gid = blockIdx.x * 4 + w;
  const int token = gid / 20, head = gid % 20;
  const int t = token & (T_ - 1);
  const bool isq = head < H_;
  const int col = isq ? head * HD_ : DIM_ + (head - H_) * HD_;
  bf16_t* p = qkv + (size_t)token * QKV_ + col;

  float v0 = (float)p[lane];
  float v1 = (float)p[lane + 64];
  float ss = v0 * v0 + v1 * v1;
#pragma unroll
  for (int off = 32; off; off >>= 1) ss += __shfl_xor(ss, off, 64);
  float r = rsqrtf(ss * (1.f / 128.f) + 1e-6f);
  v0 *= r;
  v1 *= r;
  float partner = __shfl_xor(v0, 32, 64);
  int i = lane & 31;
  float inv_freq = exp2f(-(float)(2 * i) * (1.f / 64.f) * 13.287712379549449f);
  float ang = (float)t * inv_freq;
  float cs = cosf(ang), sn = sinf(ang);
  float rot = (lane < 32) ? (v0 * cs - partner * sn) : (v0 * cs + partner * sn);
  float g = isq ? gain[head] * QSCALE : 1.f;
  p[lane] = (bf16_t)(rot * g);
  p[lane + 64] = (bf16_t)(v1 * g);
}

// ---------------------------------------------------------------------------
// V transpose: (B,T,KVH,HD) section of qkv -> vT (B,KVH,HD,T), bf16.
// ---------------------------------------------------------------------------
__global__ __launch_bounds__(256) void vtrans_kernel(const bf16_t* __restrict__ qkv,
                                                     bf16_t* __restrict__ vt) {
  const int bk = blockIdx.x;
  const int t0 = blockIdx.y * 64;
  const int b = bk >> 2, kvh = bk & 3;
  __shared__ bf16_t tile[64][132];
  const bf16_t* src = qkv + (size_t)(b * T_) * QKV_ + DIM_ + KVH_ * HD_ + kvh * HD_;
  for (int c = threadIdx.x; c < 2048; c += 256) {
    int tl = c >> 5, h4 = c & 31;
    bf16x4 v = *(const bf16x4*)(src + (size_t)(t0 + tl) * QKV_ + h4 * 4);
    *(bf16x4*)&tile[tl][h4 * 4] = v;
  }
  __syncthreads();
  bf16_t* dst = vt + (size_t)bk * HD_ * T_;
  for (int c = threadIdx.x; c < 2048; c += 256) {
    int hd = c >> 4, t4 = c & 15;
    bf16x4 v = {tile[t4 * 4 + 0][hd], tile[t4 * 4 + 1][hd],
                tile[t4 * 4 + 2][hd], tile[t4 * 4 + 3][hd]};
    *(bf16x4*)(dst + (size_t)hd * T_ + t0 + t4 * 4) = v;
  }
}

// ---------------------------------------------------------------------------
// Flash attention, S^T formulation, software-pipelined.
// Grid (8,16,4): block handles q-tiles {15-x, x} (uniform 68 iters/block,
// all 512 blocks co-resident). 4 waves x 32 q-rows. K-step = 32 keys,
// double-buffered K/V LDS staged via global_load_lds; per-iter pattern:
//   barrier (drains loads issued LAST iter) -> issue next tile -> compute.
// LDS chunk = 16B = 8 ELEMENTS; all staging dests are elem_index*8.
// ---------------------------------------------------------------------------
__global__ __launch_bounds__(256) void attn_kernel(const bf16_t* __restrict__ qkv,
                                                   const bf16_t* __restrict__ vt,
                                                   bf16_t* __restrict__ y) {
  __shared__ __align__(16) bf16_t Ks[2][32 * 128];  // [key][hd], 16B chunk slot s holds src chunk s^(key&15)
  __shared__ __align__(16) bf16_t Vs[2][128 * 32];  // [d][key], slot c holds src chunk c^((d^(d>>2))&3)
  __shared__ __align__(16) bf16_t Ps[4][32 * 40];   // per-wave P [qrow][key], stride 40

  const int tid = threadIdx.x;
  const int w = tid >> 6, lane = tid & 63;
  const int m = lane & 15, q = lane >> 4;
  const int h = blockIdx.y, b = blockIdx.z, kvh = h >> 2;

  const bf16_t* qptr = qkv + (size_t)(b * T_) * QKV_ + h * HD_;
  const bf16_t* kptr = qkv + (size_t)(b * T_) * QKV_ + DIM_ + kvh * HD_;
  const bf16_t* vptr = qkv + (size_t)(b * T_) * QKV_ + DIM_ + KVH_ * HD_ + kvh * HD_;
  const bf16_t* vtptr = vt + (size_t)(b * KVH_ + kvh) * HD_ * T_;

  // per-thread staging indices (fixed): K 512 chunks, V 512 chunks
  const int kKey0 = tid >> 4, kC0 = tid & 15;
  const int kKey1 = (256 + tid) >> 4, kC1 = tid & 15;
  const int vD0 = tid >> 2, vC0 = tid & 3;
  const int vD1 = (256 + tid) >> 2, vC1 = tid & 3;
  const int vS0 = (vD0 ^ (vD0 >> 2)) & 3, vS1 = (vD1 ^ (vD1 >> 2)) & 3;

#pragma unroll 1
  for (int ti = 0; ti < 2; ++ti) {
    const int qb = ((ti == 0) ? (15 - (int)blockIdx.x) : (int)blockIdx.x) * 128;
    const int qbw = qb + w * 32;
    const int nk = (qb >> 5) + 4;

    // Q fragments (B-operand): aq[qf][c] = Q[qbw+qf*16+m][c*32+q*8 ..+8]
    bf16x8 aq[2][4];
#pragma unroll
    for (int qf = 0; qf < 2; ++qf)
#pragma unroll
      for (int c = 0; c < 4; ++c)
        aq[qf][c] = *(const bf16x8*)(qptr + (size_t)(qbw + qf * 16 + m) * QKV_ + c * 32 + q * 8);

    f32x4 o[2][8];
#pragma unroll
    for (int qf = 0; qf < 2; ++qf)
#pragma unroll
      for (int f = 0; f < 8; ++f) o[qf][f] = (f32x4){0.f, 0.f, 0.f, 0.f};
    float m_r[2] = {-1e30f, -1e30f};
    float l_r[2] = {0.f, 0.f};

    // prefetch tile 0 (elem offset = chunk_id * 8)
    {
      gload16(kptr + (size_t)kKey0 * QKV_ + ((kC0 ^ kKey0) & 15) * 8, &Ks[0][tid * 8]);
      gload16(kptr + (size_t)kKey1 * QKV_ + ((kC1 ^ kKey1) & 15) * 8, &Ks[0][(256 + tid) * 8]);
      gload16(vtptr + (size_t)vD0 * T_ + (vC0 ^ vS0) * 8, &Vs[0][tid * 8]);
      gload16(vtptr + (size_t)vD1 * T_ + (vC1 ^ vS1) * 8, &Vs[0][(256 + tid) * 8]);
    }

#pragma unroll 1
    for (int it = 0; it < nk; ++it) {
      const int kb = it << 5;
      __syncthreads();  // drains tile-it loads (issued one full iter ago)

      if (it + 1 < nk) {  // issue tile it+1 into the other buffer
        const int kb2 = kb + 32;
        bf16_t* Kb = Ks[(it + 1) & 1];
        bf16_t* Vb = Vs[(it + 1) & 1];
        gload16(kptr + (size_t)(kb2 + kKey0) * QKV_ + ((kC0 ^ kKey0) & 15) * 8, &Kb[tid * 8]);
        gload16(kptr + (size_t)(kb2 + kKey1) * QKV_ + ((kC1 ^ kKey1) & 15) * 8, &Kb[(256 + tid) * 8]);
        gload16(vtptr + (size_t)vD0 * T_ + kb2 + (vC0 ^ vS0) * 8, &Vb[tid * 8]);
        gload16(vtptr + (size_t)vD1 * T_ + kb2 + (vC1 ^ vS1) * 8, &Vb[(256 + tid) * 8]);
      }

      if (kb > qbw + 31) continue;  // whole key-tile masked for this wave
      const bf16_t* Kb = Ks[it & 1];
      const bf16_t* Vb = Vs[it & 1];

      // ---- S^T = K . Q^T   (16 MFMA, 8 ds_read_b128)
      f32x4 S[2][2];
#pragma unroll
      for (int qf = 0; qf < 2; ++qf)
#pragma unroll
        for (int kf = 0; kf < 2; ++kf) S[qf][kf] = (f32x4){0.f, 0.f, 0.f, 0.f};
#pragma unroll
      for (int kf = 0; kf < 2; ++kf)
#pragma unroll
        for (int c = 0; c < 4; ++c) {
          bf16x8 ak = *(const bf16x8*)&Kb[(kf * 16 + m) * 128 + ((c * 4 + q) ^ m) * 8];
          S[0][kf] = __builtin_amdgcn_mfma_f32_16x16x32_bf16(ak, aq[0][c], S[0][kf], 0, 0, 0);
          S[1][kf] = __builtin_amdgcn_mfma_f32_16x16x32_bf16(ak, aq[1][c], S[1][kf], 0, 0, 0);
        }

      const bool needmask = (kb + 31) > qbw;
#pragma unroll
      for (int qf = 0; qf < 2; ++qf) {
        const int qrow = qbw + qf * 16 + m;
        if (needmask) {
#pragma unroll
          for (int kf = 0; kf < 2; ++kf)
#pragma unroll
            for (int r = 0; r < 4; ++r) {
              int key = kb + kf * 16 + q * 4 + r;
              if (key > qrow) S[qf][kf][r] = -1e30f;
            }
        }
        float t = -1e30f;
#pragma unroll
        for (int kf = 0; kf < 2; ++kf)
          t = fmaxf(t, fmaxf(fmaxf(S[qf][kf][0], S[qf][kf][1]),
                             fmaxf(S[qf][kf][2], S[qf][kf][3])));
        t = fmaxf(t, __shfl_xor(t, 16));
        t = fmaxf(t, __shfl_xor(t, 32));
        float mn = fmaxf(m_r[qf], t);
        float al = exp2f(m_r[qf] - mn);
        m_r[qf] = mn;
        float rs = 0.f;
#pragma unroll
        for (int kf = 0; kf < 2; ++kf)
#pragma unroll
          for (int r = 0; r < 4; ++r) {
            float p = exp2f(S[qf][kf][r] - mn);
            S[qf][kf][r] = p;
            rs += p;
          }
        rs += __shfl_xor(rs, 16);
        rs += __shfl_xor(rs, 32);
        l_r[qf] = l_r[qf] * al + rs;
#pragma unroll
        for (int f = 0; f < 8; ++f) {
          o[qf][f][0] *= al; o[qf][f][1] *= al; o[qf][f][2] *= al; o[qf][f][3] *= al;
        }
#pragma unroll
        for (int kf = 0; kf < 2; ++kf) {
          bf16x4 pk = {(__bf16)S[qf][kf][0], (__bf16)S[qf][kf][1],
                       (__bf16)S[qf][kf][2], (__bf16)S[qf][kf][3]};
          *(bf16x4*)&Ps[w][(qf * 16 + m) * 40 + kf * 16 + q * 4] = pk;
        }
      }
      asm volatile("s_waitcnt lgkmcnt(0)" ::: "memory");

      // ---- PV: O^T += V^T . P^T  (16 MFMA, 10 ds_read_b128)
      bf16x8 Pb[2];
#pragma unroll
      for (int qf = 0; qf < 2; ++qf)
        Pb[qf] = *(const bf16x8*)&Ps[w][(qf * 16 + m) * 40 + q * 8];
#pragma unroll
      for (int f = 0; f < 8; ++f) {
        const int d = f * 16 + m;
        bf16x8 av = *(const bf16x8*)&Vb[d * 32 + ((q ^ ((d ^ (d >> 2)) & 3)) & 3) * 8];
        o[0][f] = __builtin_amdgcn_mfma_f32_16x16x32_bf16(av, Pb[0], o[0][f], 0, 0, 0);
        o[1][f] = __builtin_amdgcn_mfma_f32_16x16x32_bf16(av, Pb[1], o[1][f], 0, 0, 0);
      }
    }

    // ---- epilogue: y = o/l minus projection onto normalized v row
#pragma unroll
    for (int qf = 0; qf < 2; ++qf) {
      const int trow = qbw + qf * 16 + m;
      const float linv = 1.f / l_r[qf];
      bf16x4 vv[8];
      float n2 = 0.f, dp = 0.f;
#pragma unroll
      for (int f = 0; f < 8; ++f) {
        vv[f] = *(const bf16x4*)(vptr + (size_t)trow * QKV_ + f * 16 + q * 4);
#pragma unroll
        for (int r = 0; r < 4; ++r) {
          float v = (float)vv[f][r];
          n2 += v * v;
          dp += o[qf][f][r] * linv * v;
        }
      }
      n2 += __shfl_xor(n2, 16); n2 += __shfl_xor(n2, 32);
      dp += __shfl_xor(dp, 16); dp += __shfl_xor(dp, 32);
      float d = fmaxf(sqrtf(n2), 1e-12f);
      float coef = dp / (d * d);
#pragma unroll
      for (int f = 0; f < 8; ++f) {
        bf16x4 yo;
#pragma unroll
        for (int r = 0; r < 4; ++r)
          yo[r] = (bf16_t)(o[qf][f][r] * linv - coef * (float)vv[f][r]);
        *(bf16x4*)(y + (size_t)(b * T_ + trow) * DIM_ + h * HD_ + f * 16 + q * 4) = yo;
      }
    }
    __syncthreads();  // protect K/V buffers before next q-tile's prefetch
  }
}

// ---------------------------------------------------------------------------
extern "C" void kernel_launch(void* const* d_in, const int* in_sizes, int n_in,
                              void* d_out, int out_size, void* d_ws, size_t ws_size,
                              hipStream_t stream) {
  const float* x = (const float*)d_in[0];
  const float* Wq = (const float*)d_in[1];
  const float* Wk = (const float*)d_in[2];
  const float* Wv = (const float*)d_in[3];
  const float* Wp = (const float*)d_in[4];
  const float* qg = (const float*)d_in[5];

  bf16_t* xbf = (bf16_t*)d_ws;                        // 8192*2048
  bf16_t* wqkv = xbf + (size_t)8192 * 2048;           // 3072*2048
  bf16_t* wproj = wqkv + (size_t)3072 * 2048;         // 2048*2048
  bf16_t* qkv = wproj + (size_t)2048 * 2048;          // 8192*3072
  bf16_t* vt = qkv + (size_t)8192 * 3072;             // 16*128*2048
  bf16_t* ybf = xbf;

  cvt_kernel<<<16384, 256, 0, stream>>>((const float4*)x, (bf16x4*)xbf, 4194304);
  cvt_kernel<<<4096, 256, 0, stream>>>((const float4*)Wq, (bf16x4*)wqkv, 1048576);
  cvt_kernel<<<1024, 256, 0, stream>>>((const float4*)Wk, (bf16x4*)(wqkv + (size_t)2048 * 2048), 262144);
  cvt_kernel<<<1024, 256, 0, stream>>>((const float4*)Wv, (bf16x4*)(wqkv + (size_t)2560 * 2048), 262144);
  cvt_kernel<<<4096, 256, 0, stream>>>((const float4*)Wp, (bf16x4*)wproj, 1048576);

  gemm_bt<<<dim3(24, 64), 256, 0, stream>>>(xbf, wqkv, qkv, 8192, 3072, 2048, 1);
  qknorm_kernel<<<40960, 256, 0, stream>>>(qkv, qg);
  vtrans_kernel<<<dim3(16, 32), 256, 0, stream>>>(qkv, vt);
  attn_kernel<<<dim3(8, 16, 4), 256, 0, stream>>>(qkv, vt, ybf);
  gemm_bt<<<dim3(16, 64), 256, 0, stream>>>(ybf, wproj, d_out, 8192, 2048, 2048, 0);
}

// Round 5
// 582.642 us; speedup vs baseline: 2.2504x; 1.0403x over previous
//
#include <hip/hip_runtime.h>
#include <cstdint>
#include <cstddef>

typedef __bf16 bf16_t;
typedef __bf16 bf16x4 __attribute__((ext_vector_type(4)));
typedef __bf16 bf16x8 __attribute__((ext_vector_type(8)));
typedef float f32x4 __attribute__((ext_vector_type(4)));

#define B_ 4
#define T_ 2048
#define DIM_ 2048
#define H_ 16
#define KVH_ 4
#define HD_ 128
#define QKV_ 3072
// SCALE * log2(e): folded into q rows in the gemm_qkv epilogue; attn uses exp2.
#define QSCALE (0.08838834764831845f * 1.4426950408889634f)

// ---------------------------------------------------------------------------
// async global->LDS, 16B per lane. LDS dest = wave-uniform base + lane*16B.
// Dest pointer arithmetic is in ELEMENTS: 8 bf16 = 16B per lane.
// ---------------------------------------------------------------------------
__device__ __forceinline__ void gload16(const bf16_t* g, bf16_t* l) {
  __builtin_amdgcn_global_load_lds(
      (const __attribute__((address_space(1))) unsigned int*)g,
      (__attribute__((address_space(3))) unsigned int*)l, 16, 0, 0);
}

// ---------------------------------------------------------------------------
// fused fp32 -> bf16 convert for all five inputs (one launch).
// Segments (float4 units): x 4194304 | Wq 1048576 | Wk 262144 | Wv 262144 | Wp 1048576
// ---------------------------------------------------------------------------
__global__ __launch_bounds__(256) void cvt_all(const float4* __restrict__ x,
                                               const float4* __restrict__ wq,
                                               const float4* __restrict__ wk,
                                               const float4* __restrict__ wv,
                                               const float4* __restrict__ wp,
                                               bf16x4* __restrict__ xb,
                                               bf16x4* __restrict__ wqkvb,
                                               bf16x4* __restrict__ wpb) {
  int i = blockIdx.x * 256 + threadIdx.x;
  const float4* s;
  bf16x4* dst;
  int off;
  if (i < 4194304) { s = x; dst = xb; off = i; }
  else if (i < 5242880) { s = wq; dst = wqkvb; off = i - 4194304; }
  else if (i < 5505024) { s = wk; dst = wqkvb + 1048576; off = i - 5242880; }
  else if (i < 5767168) { s = wv; dst = wqkvb + 1310720; off = i - 5505024; }
  else { s = wp; dst = wpb; off = i - 5767168; }
  float4 v = s[off];
  bf16x4 o = {(__bf16)v.x, (__bf16)v.y, (__bf16)v.z, (__bf16)v.w};
  dst[off] = o;
}

// ---------------------------------------------------------------------------
// GEMM: C(MxN) = A(MxK) @ B(NxK)^T, bf16 in, fp32 acc. m97 structure.
// Used for the output projection (fp32 out).
// ---------------------------------------------------------------------------
__global__ __launch_bounds__(256) void gemm_bt(const bf16_t* __restrict__ A,
                                               const bf16_t* __restrict__ B,
                                               void* __restrict__ Cp,
                                               int M, int N, int K, int out_bf16) {
  __shared__ bf16_t As[128 * 32];
  __shared__ bf16_t Bs[128 * 32];
  const int tid = threadIdx.x;
  const int w = tid >> 6, lane = tid & 63;
  const int m_lane = lane & 15, quad = lane >> 4;
  const int wr = w >> 1, wc = w & 1;
  const int rowBase = blockIdx.y * 128, colBase = blockIdx.x * 128;

  f32x4 acc[4][4];
#pragma unroll
  for (int i = 0; i < 4; ++i)
#pragma unroll
    for (int j = 0; j < 4; ++j) acc[i][j] = (f32x4){0.f, 0.f, 0.f, 0.f};

  const int nk = K >> 5;
  for (int kk = 0; kk < nk; ++kk) {
    const int k0 = kk << 5;
#pragma unroll
    for (int i2 = 0; i2 < 2; ++i2) {
      int idx = i2 * 256 + tid;
      int row = idx >> 2, kc = idx & 3;
      gload16(A + (size_t)(rowBase + row) * K + k0 + kc * 8, &As[idx * 8]);
      gload16(B + (size_t)(colBase + row) * K + k0 + kc * 8, &Bs[idx * 8]);
    }
    __syncthreads();
    bf16x8 a[4], bb[4];
#pragma unroll
    for (int i = 0; i < 4; ++i)
      a[i] = *(const bf16x8*)&As[(wr * 64 + i * 16 + m_lane) * 32 + quad * 8];
#pragma unroll
    for (int j = 0; j < 4; ++j)
      bb[j] = *(const bf16x8*)&Bs[(wc * 64 + j * 16 + m_lane) * 32 + quad * 8];
#pragma unroll
    for (int i = 0; i < 4; ++i)
#pragma unroll
      for (int j = 0; j < 4; ++j)
        acc[i][j] = __builtin_amdgcn_mfma_f32_16x16x32_bf16(a[i], bb[j], acc[i][j], 0, 0, 0);
    __syncthreads();
  }

  if (out_bf16) {
    bf16_t* C = (bf16_t*)Cp;
#pragma unroll
    for (int i = 0; i < 4; ++i)
#pragma unroll
      for (int j = 0; j < 4; ++j)
#pragma unroll
        for (int r = 0; r < 4; ++r) {
          int row = rowBase + wr * 64 + i * 16 + quad * 4 + r;
          int col = colBase + wc * 64 + j * 16 + m_lane;
          C[(size_t)row * N + col] = (bf16_t)acc[i][j][r];
        }
  } else {
    float* C = (float*)Cp;
#pragma unroll
    for (int i = 0; i < 4; ++i)
#pragma unroll
      for (int j = 0; j < 4; ++j)
#pragma unroll
        for (int r = 0; r < 4; ++r) {
          int row = rowBase + wr * 64 + i * 16 + quad * 4 + r;
          int col = colBase + wc * 64 + j * 16 + m_lane;
          C[(size_t)row * N + col] = acc[i][j][r];
        }
  }
}

// ---------------------------------------------------------------------------
// QKV GEMM with fused epilogue: M=8192, N=3072, K=2048.
// Col-tile bx: 0..15 = q heads, 16..19 = k heads, 20..23 = v heads.
// q/k tiles: RMSNorm (fp32 acc, cross-wave LDS reduce) + RoPE (+gain*QSCALE
// for q). A 128-col tile is exactly one head; RoPE pairs (d,d+32) are
// lane-local (fragment j and j+2). v tiles: raw store + transposed store
// into vt (B,KVH,HD,T) -- replaces the separate vtrans kernel.
// ---------------------------------------------------------------------------
__global__ __launch_bounds__(256) void gemm_qkv(const bf16_t* __restrict__ A,
                                                const bf16_t* __restrict__ Bw,
                                                bf16_t* __restrict__ qkv,
                                                bf16_t* __restrict__ vt,
                                                const float* __restrict__ gain) {
  __shared__ bf16_t As[128 * 32];
  __shared__ bf16_t Bs[128 * 32];
  __shared__ float ssbuf[2][128];
  const int tid = threadIdx.x;
  const int w = tid >> 6, lane = tid & 63;
  const int m = lane & 15, quad = lane >> 4;
  const int wr = w >> 1, wc = w & 1;
  const int rowBase = blockIdx.y * 128, colBase = blockIdx.x * 128;

  f32x4 acc[4][4];
#pragma unroll
  for (int i = 0; i < 4; ++i)
#pragma unroll
    for (int j = 0; j < 4; ++j) acc[i][j] = (f32x4){0.f, 0.f, 0.f, 0.f};

  for (int kk = 0; kk < 64; ++kk) {
    const int k0 = kk << 5;
#pragma unroll
    for (int i2 = 0; i2 < 2; ++i2) {
      int idx = i2 * 256 + tid;
      int row = idx >> 2, kc = idx & 3;
      gload16(A + (size_t)(rowBase + row) * 2048 + k0 + kc * 8, &As[idx * 8]);
      gload16(Bw + (size_t)(colBase + row) * 2048 + k0 + kc * 8, &Bs[idx * 8]);
    }
    __syncthreads();
    bf16x8 a[4], bb[4];
#pragma unroll
    for (int i = 0; i < 4; ++i)
      a[i] = *(const bf16x8*)&As[(wr * 64 + i * 16 + m) * 32 + quad * 8];
#pragma unroll
    for (int j = 0; j < 4; ++j)
      bb[j] = *(const bf16x8*)&Bs[(wc * 64 + j * 16 + m) * 32 + quad * 8];
#pragma unroll
    for (int i = 0; i < 4; ++i)
#pragma unroll
      for (int j = 0; j < 4; ++j)
        acc[i][j] = __builtin_amdgcn_mfma_f32_16x16x32_bf16(a[i], bb[j], acc[i][j], 0, 0, 0);
    __syncthreads();
  }

  const int bx = blockIdx.x;
  if (bx < 20) {
    // ---- q/k epilogue: RMSNorm + RoPE
    const float g = (bx < 16) ? gain[bx] * QSCALE : 1.0f;
    // per-row sum of squares: in-lane (4 cols) -> 16-lane tree -> LDS cross-wave
#pragma unroll
    for (int i = 0; i < 4; ++i) {
      float ssp[4];
#pragma unroll
      for (int r = 0; r < 4; ++r) {
        float s = 0.f;
#pragma unroll
        for (int j = 0; j < 4; ++j) s += acc[i][j][r] * acc[i][j][r];
#pragma unroll
        for (int off = 1; off <= 8; off <<= 1) s += __shfl_xor(s, off);
        ssp[r] = s;
      }
      if (m == 0) {
#pragma unroll
        for (int r = 0; r < 4; ++r) ssbuf[wc][wr * 64 + i * 16 + quad * 4 + r] = ssp[r];
      }
    }
    __syncthreads();
    // inv_freq for this lane's two rope pair-indices p=m and p=16+m
    const float if0 = exp2f(-(float)m * 0.4152410118609203f);
    const float if1 = exp2f(-(float)(16 + m) * 0.4152410118609203f);
#pragma unroll
    for (int i = 0; i < 4; ++i) {
#pragma unroll
      for (int r = 0; r < 4; ++r) {
        const int ridx = wr * 64 + i * 16 + quad * 4 + r;
        const int row = rowBase + ridx;
        const float rn = rsqrtf((ssbuf[0][ridx] + ssbuf[1][ridx]) * (1.f / 128.f) + 1e-6f);
        float v0 = acc[i][0][r] * rn, v1 = acc[i][1][r] * rn;
        float v2 = acc[i][2][r] * rn, v3 = acc[i][3][r] * rn;
        float o0 = v0, o1 = v1, o2 = v2, o3 = v3;
        if (wc == 0) {  // cols 0..63 of head: rotate pairs (d, d+32)
          const float t = (float)(row & (T_ - 1));
          const float a0 = t * if0, a1 = t * if1;
          const float c0 = cosf(a0), s0 = sinf(a0);
          const float c1 = cosf(a1), s1 = sinf(a1);
          o0 = v0 * c0 - v2 * s0;
          o1 = v1 * c1 - v3 * s1;
          o2 = v2 * c0 + v0 * s0;
          o3 = v3 * c1 + v1 * s1;
        }
        bf16_t* out = qkv + (size_t)row * QKV_ + colBase + wc * 64 + m;
        out[0]  = (bf16_t)(o0 * g);
        out[16] = (bf16_t)(o1 * g);
        out[32] = (bf16_t)(o2 * g);
        out[48] = (bf16_t)(o3 * g);
      }
    }
  } else {
    // ---- v epilogue: raw row-major store + transposed store into vt
    const int kvh = bx - 20;
#pragma unroll
    for (int i = 0; i < 4; ++i)
#pragma unroll
      for (int j = 0; j < 4; ++j) {
        const int row0 = rowBase + wr * 64 + i * 16 + quad * 4;
        const int d = wc * 64 + j * 16 + m;
        bf16x4 pv;
#pragma unroll
        for (int r = 0; r < 4; ++r) {
          pv[r] = (bf16_t)acc[i][j][r];
          qkv[(size_t)(row0 + r) * QKV_ + colBase + d] = pv[r];
        }
        const int b = row0 >> 11, t0 = row0 & (T_ - 1);
        *(bf16x4*)(vt + ((size_t)(b * KVH_ + kvh) * HD_ + d) * T_ + t0) = pv;
      }
  }
}

// ---------------------------------------------------------------------------
// Flash attention, S^T formulation, software-pipelined (unchanged structure
// from R4). Grid (8,16,4): block handles q-tiles {15-x, x} (uniform 68
// iters/block, 512 blocks co-resident). 4 waves x 32 q-rows. K-step 32,
// double-buffered K/V LDS via global_load_lds. R5: LDS read offsets hoisted
// out of the K-loop; o-rescale vectorized (f32x4 * scalar).
// ---------------------------------------------------------------------------
__global__ __launch_bounds__(256) void attn_kernel(const bf16_t* __restrict__ qkv,
                                                   const bf16_t* __restrict__ vt,
                                                   bf16_t* __restrict__ y) {
  __shared__ __align__(16) bf16_t Ks[2][32 * 128];  // [key][hd], chunk slot s holds src chunk s^(key&15)
  __shared__ __align__(16) bf16_t Vs[2][128 * 32];  // [d][key], slot c holds src chunk c^((d^(d>>2))&3)
  __shared__ __align__(16) bf16_t Ps[4][32 * 40];   // per-wave P [qrow][key], stride 40

  const int tid = threadIdx.x;
  const int w = tid >> 6, lane = tid & 63;
  const int m = lane & 15, q = lane >> 4;
  const int h = blockIdx.y, b = blockIdx.z, kvh = h >> 2;

  const bf16_t* qptr = qkv + (size_t)(b * T_) * QKV_ + h * HD_;
  const bf16_t* kptr = qkv + (size_t)(b * T_) * QKV_ + DIM_ + kvh * HD_;
  const bf16_t* vptr = qkv + (size_t)(b * T_) * QKV_ + DIM_ + KVH_ * HD_ + kvh * HD_;
  const bf16_t* vtptr = vt + (size_t)(b * KVH_ + kvh) * HD_ * T_;

  // per-thread staging indices (fixed): K 512 chunks, V 512 chunks
  const int kKey0 = tid >> 4, kC0 = tid & 15;
  const int kKey1 = (256 + tid) >> 4, kC1 = tid & 15;
  const int vD0 = tid >> 2, vC0 = tid & 3;
  const int vD1 = (256 + tid) >> 2, vC1 = tid & 3;
  const int vS0 = (vD0 ^ (vD0 >> 2)) & 3, vS1 = (vD1 ^ (vD1 >> 2)) & 3;

  // hoisted LDS read offsets (loop-invariant; elements)
  int koff[2][4], voff[8], poff[2];
#pragma unroll
  for (int kf = 0; kf < 2; ++kf)
#pragma unroll
    for (int c = 0; c < 4; ++c)
      koff[kf][c] = (kf * 16 + m) * 128 + (((c * 4 + q) ^ m) & 15) * 8;
#pragma unroll
  for (int f = 0; f < 8; ++f) {
    const int d = f * 16 + m;
    voff[f] = d * 32 + ((q ^ ((d ^ (d >> 2)) & 3)) & 3) * 8;
  }
#pragma unroll
  for (int qf = 0; qf < 2; ++qf) poff[qf] = (qf * 16 + m) * 40 + q * 8;

#pragma unroll 1
  for (int ti = 0; ti < 2; ++ti) {
    const int qb = ((ti == 0) ? (15 - (int)blockIdx.x) : (int)blockIdx.x) * 128;
    const int qbw = qb + w * 32;
    const int nk = (qb >> 5) + 4;

    // Q fragments (B-operand): aq[qf][c] = Q[qbw+qf*16+m][c*32+q*8 ..+8]
    bf16x8 aq[2][4];
#pragma unroll
    for (int qf = 0; qf < 2; ++qf)
#pragma unroll
      for (int c = 0; c < 4; ++c)
        aq[qf][c] = *(const bf16x8*)(qptr + (size_t)(qbw + qf * 16 + m) * QKV_ + c * 32 + q * 8);

    f32x4 o[2][8];
#pragma unroll
    for (int qf = 0; qf < 2; ++qf)
#pragma unroll
      for (int f = 0; f < 8; ++f) o[qf][f] = (f32x4){0.f, 0.f, 0.f, 0.f};
    float m_r[2] = {-1e30f, -1e30f};
    float l_r[2] = {0.f, 0.f};

    // prefetch tile 0 (elem offset = chunk_id * 8)
    {
      gload16(kptr + (size_t)kKey0 * QKV_ + ((kC0 ^ kKey0) & 15) * 8, &Ks[0][tid * 8]);
      gload16(kptr + (size_t)kKey1 * QKV_ + ((kC1 ^ kKey1) & 15) * 8, &Ks[0][(256 + tid) * 8]);
      gload16(vtptr + (size_t)vD0 * T_ + (vC0 ^ vS0) * 8, &Vs[0][tid * 8]);
      gload16(vtptr + (size_t)vD1 * T_ + (vC1 ^ vS1) * 8, &Vs[0][(256 + tid) * 8]);
    }

#pragma unroll 1
    for (int it = 0; it < nk; ++it) {
      const int kb = it << 5;
      __syncthreads();  // drains tile-it loads (issued one full iter ago)

      if (it + 1 < nk) {  // issue tile it+1 into the other buffer
        const int kb2 = kb + 32;
        bf16_t* Kb = Ks[(it + 1) & 1];
        bf16_t* Vb = Vs[(it + 1) & 1];
        gload16(kptr + (size_t)(kb2 + kKey0) * QKV_ + ((kC0 ^ kKey0) & 15) * 8, &Kb[tid * 8]);
        gload16(kptr + (size_t)(kb2 + kKey1) * QKV_ + ((kC1 ^ kKey1) & 15) * 8, &Kb[(256 + tid) * 8]);
        gload16(vtptr + (size_t)vD0 * T_ + kb2 + (vC0 ^ vS0) * 8, &Vb[tid * 8]);
        gload16(vtptr + (size_t)vD1 * T_ + kb2 + (vC1 ^ vS1) * 8, &Vb[(256 + tid) * 8]);
      }

      if (kb > qbw + 31) continue;  // whole key-tile masked for this wave
      const bf16_t* Kb = Ks[it & 1];
      const bf16_t* Vb = Vs[it & 1];

      // ---- S^T = K . Q^T   (16 MFMA, 8 ds_read_b128)
      f32x4 S[2][2];
#pragma unroll
      for (int qf = 0; qf < 2; ++qf)
#pragma unroll
        for (int kf = 0; kf < 2; ++kf) S[qf][kf] = (f32x4){0.f, 0.f, 0.f, 0.f};
#pragma unroll
      for (int kf = 0; kf < 2; ++kf)
#pragma unroll
        for (int c = 0; c < 4; ++c) {
          bf16x8 ak = *(const bf16x8*)&Kb[koff[kf][c]];
          S[0][kf] = __builtin_amdgcn_mfma_f32_16x16x32_bf16(ak, aq[0][c], S[0][kf], 0, 0, 0);
          S[1][kf] = __builtin_amdgcn_mfma_f32_16x16x32_bf16(ak, aq[1][c], S[1][kf], 0, 0, 0);
        }

      const bool needmask = (kb + 31) > qbw;
#pragma unroll
      for (int qf = 0; qf < 2; ++qf) {
        const int qrow = qbw + qf * 16 + m;
        if (needmask) {
#pragma unroll
          for (int kf = 0; kf < 2; ++kf)
#pragma unroll
            for (int r = 0; r < 4; ++r) {
              int key = kb + kf * 16 + q * 4 + r;
              if (key > qrow) S[qf][kf][r] = -1e30f;
            }
        }
        float t = -1e30f;
#pragma unroll
        for (int kf = 0; kf < 2; ++kf)
          t = fmaxf(t, fmaxf(fmaxf(S[qf][kf][0], S[qf][kf][1]),
                             fmaxf(S[qf][kf][2], S[qf][kf][3])));
        t = fmaxf(t, __shfl_xor(t, 16));
        t = fmaxf(t, __shfl_xor(t, 32));
        float mn = fmaxf(m_r[qf], t);
        float al = exp2f(m_r[qf] - mn);
        m_r[qf] = mn;
        float rs = 0.f;
#pragma unroll
        for (int kf = 0; kf < 2; ++kf)
#pragma unroll
          for (int r = 0; r < 4; ++r) {
            float p = exp2f(S[qf][kf][r] - mn);
            S[qf][kf][r] = p;
            rs += p;
          }
        rs += __shfl_xor(rs, 16);
        rs += __shfl_xor(rs, 32);
        l_r[qf] = l_r[qf] * al + rs;
#pragma unroll
        for (int f = 0; f < 8; ++f) o[qf][f] = o[qf][f] * al;  // f32x4 * scalar
#pragma unroll
        for (int kf = 0; kf < 2; ++kf) {
          bf16x4 pk = {(__bf16)S[qf][kf][0], (__bf16)S[qf][kf][1],
                       (__bf16)S[qf][kf][2], (__bf16)S[qf][kf][3]};
          *(bf16x4*)&Ps[w][(qf * 16 + m) * 40 + kf * 16 + q * 4] = pk;
        }
      }
      asm volatile("s_waitcnt lgkmcnt(0)" ::: "memory");

      // ---- PV: O^T += V^T . P^T  (16 MFMA, 10 ds_read_b128)
      bf16x8 Pb[2];
#pragma unroll
      for (int qf = 0; qf < 2; ++qf)
        Pb[qf] = *(const bf16x8*)&Ps[w][poff[qf]];
#pragma unroll
      for (int f = 0; f < 8; ++f) {
        bf16x8 av = *(const bf16x8*)&Vb[voff[f]];
        o[0][f] = __builtin_amdgcn_mfma_f32_16x16x32_bf16(av, Pb[0], o[0][f], 0, 0, 0);
        o[1][f] = __builtin_amdgcn_mfma_f32_16x16x32_bf16(av, Pb[1], o[1][f], 0, 0, 0);
      }
    }

    // ---- epilogue: y = o/l minus projection onto normalized v row
#pragma unroll
    for (int qf = 0; qf < 2; ++qf) {
      const int trow = qbw + qf * 16 + m;
      const float linv = 1.f / l_r[qf];
      bf16x4 vv[8];
      float n2 = 0.f, dp = 0.f;
#pragma unroll
      for (int f = 0; f < 8; ++f) {
        vv[f] = *(const bf16x4*)(vptr + (size_t)trow * QKV_ + f * 16 + q * 4);
#pragma unroll
        for (int r = 0; r < 4; ++r) {
          float v = (float)vv[f][r];
          n2 += v * v;
          dp += o[qf][f][r] * linv * v;
        }
      }
      n2 += __shfl_xor(n2, 16); n2 += __shfl_xor(n2, 32);
      dp += __shfl_xor(dp, 16); dp += __shfl_xor(dp, 32);
      float d = fmaxf(sqrtf(n2), 1e-12f);
      float coef = dp / (d * d);
#pragma unroll
      for (int f = 0; f < 8; ++f) {
        bf16x4 yo;
#pragma unroll
        for (int r = 0; r < 4; ++r)
          yo[r] = (bf16_t)(o[qf][f][r] * linv - coef * (float)vv[f][r]);
        *(bf16x4*)(y + (size_t)(b * T_ + trow) * DIM_ + h * HD_ + f * 16 + q * 4) = yo;
      }
    }
    __syncthreads();  // protect K/V buffers before next q-tile's prefetch
  }
}

// ---------------------------------------------------------------------------
extern "C" void kernel_launch(void* const* d_in, const int* in_sizes, int n_in,
                              void* d_out, int out_size, void* d_ws, size_t ws_size,
                              hipStream_t stream) {
  const float* x = (const float*)d_in[0];
  const float* Wq = (const float*)d_in[1];
  const float* Wk = (const float*)d_in[2];
  const float* Wv = (const float*)d_in[3];
  const float* Wp = (const float*)d_in[4];
  const float* qg = (const float*)d_in[5];

  bf16_t* xbf = (bf16_t*)d_ws;                        // 8192*2048
  bf16_t* wqkv = xbf + (size_t)8192 * 2048;           // 3072*2048
  bf16_t* wproj = wqkv + (size_t)3072 * 2048;         // 2048*2048
  bf16_t* qkv = wproj + (size_t)2048 * 2048;          // 8192*3072
  bf16_t* vt = qkv + (size_t)8192 * 3072;             // 16*128*2048
  bf16_t* ybf = xbf;                                  // reuse after gemm_qkv

  cvt_all<<<26624, 256, 0, stream>>>((const float4*)x, (const float4*)Wq,
                                     (const float4*)Wk, (const float4*)Wv,
                                     (const float4*)Wp, (bf16x4*)xbf,
                                     (bf16x4*)wqkv, (bf16x4*)wproj);
  gemm_qkv<<<dim3(24, 64), 256, 0, stream>>>(xbf, wqkv, qkv, vt, qg);
  attn_kernel<<<dim3(8, 16, 4), 256, 0, stream>>>(qkv, vt, ybf);
  gemm_bt<<<dim3(16, 64), 256, 0, stream>>>(ybf, wproj, d_out, 8192, 2048, 2048, 0);
}